// Round 4
// baseline (601.036 us; speedup 1.0000x reference)
//
#include <hip/hip_runtime.h>

#define N_NODES 8192
#define CAP 128   // neighbor capacity; Binomial(8192,1/256): P(deg>128) ~ 0
#define TILE 32
constexpr int AST = 132; // activation LDS row stride (floats), 16B-aligned, padded
constexpr int WST = 129; // weight LDS row stride (k-major), +1 pad

// ---------------------------------------------------------------------------
// Kernel 1: adj scan -> CSR. One row per 256-thread block.
// Phase 1: all 8 uint4 loads consumed by a branchless per-lane popcount
//          (no stores interleaved with pending loads -> clean vmcnt pipeline).
// Phase 2: wave prefix-scan + ONE LDS atomic per wave for the base offset.
// Phase 3: emit nonzero columns from registers (all loads retired by now).
// ---------------------------------------------------------------------------
__global__ __launch_bounds__(256) void scan_kernel(
    const float* __restrict__ adj, int* __restrict__ cnt,
    int* __restrict__ nbr, float* __restrict__ dinv) {
  __shared__ int s_base;
  const int t = threadIdx.x;
  const int row = blockIdx.x;
  if (t == 0) s_base = 0;
  __syncthreads();

  const uint4* rowp = (const uint4*)(adj + (size_t)row * N_NODES);
  uint4 v[8];
#pragma unroll
  for (int i = 0; i < 8; ++i) v[i] = rowp[t + i * 256];  // 8 loads in flight

  // ---- phase 1: branchless per-lane nonzero count (consumes all loads) ----
  int c = 0;
#pragma unroll
  for (int i = 0; i < 8; ++i) {
    c += (v[i].x != 0u) + (v[i].y != 0u) + (v[i].z != 0u) + (v[i].w != 0u);
  }

  // ---- phase 2: wave-inclusive prefix scan of c, one atomic per wave ----
  const int lane = t & 63;
  int incl = c;
#pragma unroll
  for (int s = 1; s < 64; s <<= 1) {
    int n = __shfl_up(incl, s);
    if (lane >= s) incl += n;
  }
  int wave_total = __shfl(incl, 63);
  int wave_base;
  if (lane == 63) wave_base = atomicAdd(&s_base, wave_total);
  wave_base = __shfl(wave_base, 63);
  int off = wave_base + incl - c;  // exclusive per-lane start

  // ---- phase 3: emit (rare; loads all retired, stores don't mix) ----
  int* nbr_row = nbr + row * CAP;
#pragma unroll
  for (int i = 0; i < 8; ++i) {
    if (v[i].x | v[i].y | v[i].z | v[i].w) {
      const int col = (t + i * 256) * 4;
      if (v[i].x) { if (off < CAP) nbr_row[off] = col + 0; ++off; }
      if (v[i].y) { if (off < CAP) nbr_row[off] = col + 1; ++off; }
      if (v[i].z) { if (off < CAP) nbr_row[off] = col + 2; ++off; }
      if (v[i].w) { if (off < CAP) nbr_row[off] = col + 3; ++off; }
    }
  }

  __syncthreads();
  if (t == 0) {
    cnt[row] = s_base;
    dinv[row] = rsqrtf((float)s_base + 1.0f);
  }
}

// ---------------------------------------------------------------------------
// Fused LDS-resident MLP layer for a TILE of 32 nodes.
// ---------------------------------------------------------------------------
template <int K, int KSPLIT, int F, bool RELU, bool BIAS, bool MASK>
__device__ __forceinline__ void layer_op(
    const float (*__restrict__ A0)[AST], const float (*__restrict__ A1)[AST],
    float (*__restrict__ Aout)[AST], float (*__restrict__ Wb)[WST],
    const float* __restrict__ W, const float* __restrict__ bias,
    float* __restrict__ gout, const float* __restrict__ rowmask,
    int n0, int t) {
  constexpr int KC = 32;
  constexpr int NCH = K / KC;
  constexpr int RS = 256 / F;     // rows per sweep
  constexpr int RPT = TILE / RS;  // accumulators per thread
  const int c = t % F;
  const int rb = t / F;
  float acc[RPT];
#pragma unroll
  for (int i = 0; i < RPT; ++i) acc[i] = 0.f;

  for (int ch = 0; ch < NCH; ++ch) {
#pragma unroll
    for (int i = 0; i < (F * KC + 255) / 256; ++i) {  // stage W chunk, k-major
      int lin = t + i * 256;
      if ((F * KC) % 256 == 0 || lin < F * KC) {
        int k = lin % KC, f = lin / KC;
        Wb[k][f] = W[(size_t)f * K + ch * KC + k];
      }
    }
    __syncthreads();
    const float (*__restrict__ As)[AST] = (ch * KC < KSPLIT) ? A0 : A1;
    const int kb = (ch * KC < KSPLIT) ? ch * KC : ch * KC - KSPLIT;
#pragma unroll
    for (int kg = 0; kg < KC / 4; ++kg) {
      float w0 = Wb[kg * 4 + 0][c];
      float w1 = Wb[kg * 4 + 1][c];
      float w2 = Wb[kg * 4 + 2][c];
      float w3 = Wb[kg * 4 + 3][c];
#pragma unroll
      for (int i = 0; i < RPT; ++i) {
        const float4 a = *(const float4*)&As[rb + i * RS][kb + kg * 4];
        acc[i] = fmaf(a.x, w0, acc[i]);
        acc[i] = fmaf(a.y, w1, acc[i]);
        acc[i] = fmaf(a.z, w2, acc[i]);
        acc[i] = fmaf(a.w, w3, acc[i]);
      }
    }
    __syncthreads();
  }
#pragma unroll
  for (int i = 0; i < RPT; ++i) {
    float v = acc[i];
    if (BIAS) v += bias[c];
    if (RELU) v = fmaxf(v, 0.f);
    int node = n0 + rb + i * RS;
    if (MASK) v *= rowmask[node];
    if (Aout) Aout[rb + i * RS][c] = v;
    if (gout) gout[(size_t)node * F + c] = v;
  }
}

// ---------------------------------------------------------------------------
// Kernel 2: encoder x -> h1 -> h -> msg
// ---------------------------------------------------------------------------
__global__ __launch_bounds__(256) void encode_kernel(
    const float* __restrict__ x,
    const float* __restrict__ w1, const float* __restrict__ b1,
    const float* __restrict__ w2, const float* __restrict__ b2,
    const float* __restrict__ wg,
    float* __restrict__ h_out, float* __restrict__ msg_out) {
  __shared__ float bufA[TILE][AST];
  __shared__ float bufB[TILE][AST];
  __shared__ float Wb[32][WST];
  const int t = threadIdx.x;
  const int n0 = blockIdx.x * TILE;
  {  // stage x tile: 32x32 floats = 256 float4, one per thread
    int row = t >> 3, k4 = (t & 7) * 4;
    *(float4*)&bufA[row][k4] = *(const float4*)&x[(size_t)(n0 + row) * 32 + k4];
  }
  layer_op<32, 32, 64, true, true, false>(bufA, nullptr, bufB, Wb, w1, b1, nullptr, nullptr, n0, t);
  layer_op<64, 64, 128, true, true, false>(bufB, nullptr, bufA, Wb, w2, b2, h_out, nullptr, n0, t);
  layer_op<128, 128, 128, false, false, false>(bufA, nullptr, nullptr, Wb, wg, nullptr, msg_out, nullptr, n0, t);
}

// ---------------------------------------------------------------------------
// Kernel 3: g1 = relu(dinv_i * (dinv_i*msg_i + sum_j dinv_j*msg_j) + bg)
// ---------------------------------------------------------------------------
__global__ __launch_bounds__(128) void agg_kernel(
    const int* __restrict__ cnt, const int* __restrict__ nbr,
    const float* __restrict__ msg, const float* __restrict__ dinv,
    const float* __restrict__ bg, const float* __restrict__ adj,
    float* __restrict__ g1) {
  const int row = blockIdx.x;
  const int t = threadIdx.x;  // 0..127
  float acc = dinv[row] * msg[(size_t)row * 128 + t];  // self-loop
  const int c = cnt[row];
  if (c <= CAP) {
    int i = 0;
    for (; i + 4 <= c; i += 4) {
      int j0 = nbr[row * CAP + i + 0];
      int j1 = nbr[row * CAP + i + 1];
      int j2 = nbr[row * CAP + i + 2];
      int j3 = nbr[row * CAP + i + 3];
      float a0 = dinv[j0] * msg[(size_t)j0 * 128 + t];
      float a1 = dinv[j1] * msg[(size_t)j1 * 128 + t];
      float a2 = dinv[j2] * msg[(size_t)j2 * 128 + t];
      float a3 = dinv[j3] * msg[(size_t)j3 * 128 + t];
      acc += (a0 + a1) + (a2 + a3);
    }
    for (; i < c; ++i) {
      int j = nbr[row * CAP + i];
      acc += dinv[j] * msg[(size_t)j * 128 + t];
    }
  } else {  // statistically unreachable dense fallback
    for (int col = 0; col < N_NODES; ++col) {
      if (adj[(size_t)row * N_NODES + col] != 0.f) acc += dinv[col] * msg[(size_t)col * 128 + t];
    }
  }
  float v = fmaf(dinv[row], acc, bg[t]);
  g1[(size_t)row * 128 + t] = fmaxf(v, 0.f);
}

// ---------------------------------------------------------------------------
// Kernel 4: fused decoder g1 -> g2 -> p1([g2|h]) -> p2 -> out * mask
// ---------------------------------------------------------------------------
__global__ __launch_bounds__(256) void decode_kernel(
    const float* __restrict__ g1, const float* __restrict__ h,
    const float* __restrict__ wd, const float* __restrict__ bd,
    const float* __restrict__ wp1, const float* __restrict__ bp1,
    const float* __restrict__ wp2, const float* __restrict__ bp2,
    const float* __restrict__ wo, const float* __restrict__ bo,
    const float* __restrict__ mask, float* __restrict__ out) {
  __shared__ float bufA[TILE][AST];
  __shared__ float bufB[TILE][AST];
  __shared__ float bufH[TILE][AST];
  __shared__ float Wb[32][WST];
  const int t = threadIdx.x;
  const int n0 = blockIdx.x * TILE;
#pragma unroll
  for (int i = 0; i < 4; ++i) {  // stage g1 tile and h tile (32x128 each)
    int lin = t + i * 256;
    int row = lin >> 5, k4 = (lin & 31) * 4;
    *(float4*)&bufA[row][k4] = *(const float4*)&g1[(size_t)(n0 + row) * 128 + k4];
    *(float4*)&bufH[row][k4] = *(const float4*)&h[(size_t)(n0 + row) * 128 + k4];
  }
  layer_op<128, 128, 128, true, true, false>(bufA, nullptr, bufB, Wb, wd, bd, nullptr, nullptr, n0, t);   // g2
  layer_op<256, 128, 128, true, true, false>(bufB, bufH, bufA, Wb, wp1, bp1, nullptr, nullptr, n0, t);    // p1
  layer_op<128, 128, 64, true, true, false>(bufA, nullptr, bufB, Wb, wp2, bp2, nullptr, nullptr, n0, t);  // p2
  layer_op<64, 64, 8, false, true, true>(bufB, nullptr, nullptr, Wb, wo, bo, out, mask, n0, t);           // out
}

extern "C" void kernel_launch(void* const* d_in, const int* in_sizes, int n_in,
                              void* d_out, int out_size, void* d_ws, size_t ws_size,
                              hipStream_t stream) {
  const float* x    = (const float*)d_in[0];
  const float* adj  = (const float*)d_in[1];
  const float* mask = (const float*)d_in[2];
  const float* w1   = (const float*)d_in[3];
  const float* b1   = (const float*)d_in[4];
  const float* w2   = (const float*)d_in[5];
  const float* b2   = (const float*)d_in[6];
  const float* wg   = (const float*)d_in[7];
  const float* bg   = (const float*)d_in[8];
  const float* wd   = (const float*)d_in[9];
  const float* bd   = (const float*)d_in[10];
  const float* wp1  = (const float*)d_in[11];
  const float* bp1  = (const float*)d_in[12];
  const float* wp2  = (const float*)d_in[13];
  const float* bp2  = (const float*)d_in[14];
  const float* wo   = (const float*)d_in[15];
  const float* bo   = (const float*)d_in[16];
  float* out = (float*)d_out;

  float* ws = (float*)d_ws;
  float* h    = ws; ws += (size_t)N_NODES * 128;
  float* msg  = ws; ws += (size_t)N_NODES * 128;
  float* g1   = ws; ws += (size_t)N_NODES * 128;
  float* dinv = ws; ws += N_NODES;
  int* cnt = (int*)ws; ws += N_NODES;
  int* nbr = (int*)ws;  // N_NODES * CAP ints

  scan_kernel<<<N_NODES, 256, 0, stream>>>(adj, cnt, nbr, dinv);
  encode_kernel<<<N_NODES / TILE, 256, 0, stream>>>(x, w1, b1, w2, b2, wg, h, msg);
  agg_kernel<<<N_NODES, 128, 0, stream>>>(cnt, nbr, msg, dinv, bg, adj, g1);
  decode_kernel<<<N_NODES / TILE, 256, 0, stream>>>(
      g1, h, wd, bd, wp1, bp1, wp2, bp2, wo, bo, mask, out);
}